// Round 7
// baseline (151.215 us; speedup 1.0000x reference)
//
#include <hip/hip_runtime.h>

typedef __attribute__((ext_vector_type(8))) short short8;
typedef __attribute__((ext_vector_type(4))) float float4v;

#define BATCH 16
#define CDIM 2048
#define LDIM 64
#define BSTRIDE (CDIM * LDIM) /* 131072 elems per batch */
#define EPITCH 40 /* ushorts per E row */
#define DPITCH 36 /* floats per Dinv row */

__device__ __forceinline__ float bf2f(unsigned short u) {
    return __uint_as_float(((unsigned int)u) << 16);
}
__device__ __forceinline__ unsigned short f2bf(float f) {
    unsigned int x = __float_as_uint(f);
    x += 0x7fffu + ((x >> 16) & 1u); // RNE
    return (unsigned short)(x >> 16);
}

// ---- Prepass (3072 blocks x 256):
//  [0,1024)    zero out (8 MB)
//  [1024,2048) q*0.125 -> swizzled bf16 (chunk j at j^(m&7) within 128B row)
//  [2048,2560) k (64i x 2048n) -> kT[b][n][i] bf16, chunk-swizzled
//  [2560,3072) v (2048n x 64j) -> vS[b][nb][j][nn] bf16, chunk-swizzled
__global__ __launch_bounds__(256) void prepass_kernel(
    const float* __restrict__ q, const float* __restrict__ k, const float* __restrict__ v,
    float* __restrict__ out, unsigned short* __restrict__ qb,
    unsigned short* __restrict__ kT, unsigned short* __restrict__ vS)
{
    __shared__ unsigned short T[64][68];
    const int bx = blockIdx.x;
    const int t = threadIdx.x;

    if (bx < 1024) {
        float4v z = (float4v){0.f, 0.f, 0.f, 0.f};
        float4v* o = (float4v*)out + (size_t)bx * 512 + t * 2;
        o[0] = z; o[1] = z;
    } else if (bx < 2048) {
        int i = (bx - 1024) * 256 + t; // one 16B out-chunk (8 bf16) per thread
        const float4v* src = (const float4v*)q + (size_t)i * 2;
        float4v x0 = src[0], x1 = src[1];
        unsigned int u0 = f2bf(x0[0] * 0.125f) | ((unsigned)f2bf(x0[1] * 0.125f) << 16);
        unsigned int u1 = f2bf(x0[2] * 0.125f) | ((unsigned)f2bf(x0[3] * 0.125f) << 16);
        unsigned int u2 = f2bf(x1[0] * 0.125f) | ((unsigned)f2bf(x1[1] * 0.125f) << 16);
        unsigned int u3 = f2bf(x1[2] * 0.125f) | ((unsigned)f2bf(x1[3] * 0.125f) << 16);
        int b = i >> 14, r = i & 16383, m = r >> 3, j = r & 7;
        *(uint4*)(qb + (size_t)b * BSTRIDE + m * 64 + (j ^ (m & 7)) * 8) =
            make_uint4(u0, u1, u2, u3);
    } else if (bx < 2560) { // k-transpose: tile = all 64 i x 64 n
        int idx = bx - 2048, b = idx >> 5, n0 = (idx & 31) * 64;
        const float* src = k + (size_t)b * BSTRIDE + (size_t)(t >> 2) * 2048 + n0 + (t & 3) * 16;
#pragma unroll
        for (int kk = 0; kk < 4; kk++) {
            float4v x = *(const float4v*)(src + kk * 4);
#pragma unroll
            for (int e = 0; e < 4; e++)
                T[t >> 2][(t & 3) * 16 + kk * 4 + e] = f2bf(x[e]);
        }
        __syncthreads();
        unsigned short* dst = kT + (size_t)b * BSTRIDE;
        int n = t & 63;
#pragma unroll
        for (int jj = 0; jj < 2; jj++) {
            int j = (t >> 6) * 2 + jj;
            ushort4 g0, g1;
#pragma unroll
            for (int e = 0; e < 4; e++) { g0[e] = T[j * 8 + e][n]; g1[e] = T[j * 8 + 4 + e][n]; }
            *(uint4*)(dst + (size_t)(n0 + n) * 64 + (j ^ (n & 7)) * 8) =
                make_uint4(g0.x | ((unsigned)g0.y << 16), g0.z | ((unsigned)g0.w << 16),
                           g1.x | ((unsigned)g1.y << 16), g1.z | ((unsigned)g1.w << 16));
        }
    } else { // v-transpose: tile = 64 n x 64 j
        int idx = bx - 2560, b = idx >> 5, n0 = (idx & 31) * 64;
        const float* src = v + (size_t)b * BSTRIDE + (size_t)n0 * 64 +
                           (size_t)(t >> 2) * 64 + (t & 3) * 16;
#pragma unroll
        for (int kk = 0; kk < 4; kk++) {
            float4v x = *(const float4v*)(src + kk * 4);
#pragma unroll
            for (int e = 0; e < 4; e++)
                T[t >> 2][(t & 3) * 16 + kk * 4 + e] = f2bf(x[e]); // T[n][j]
        }
        __syncthreads();
        unsigned short* dst = vS + (size_t)b * BSTRIDE;
        int j = t & 63, qc = t >> 6;
#pragma unroll
        for (int nb = 0; nb < 2; nb++) {
            ushort4 g0, g1;
#pragma unroll
            for (int e = 0; e < 4; e++) {
                g0[e] = T[nb * 32 + qc * 8 + e][j];
                g1[e] = T[nb * 32 + qc * 8 + 4 + e][j];
            }
            *(uint4*)(dst + (size_t)(n0 / 32 + nb) * 2048 + j * 32 + (qc ^ (j & 3)) * 8) =
                make_uint4(g0.x | ((unsigned)g0.y << 16), g0.z | ((unsigned)g0.w << 16),
                           g1.x | ((unsigned)g1.y << 16), g1.z | ((unsigned)g1.w << 16));
        }
    }
}

// ---- Fused attention: one kernel computes S, batch-softmax denominator, and P@V.
// Grid 512 = 128 mt (MT=16) x 4 ns (512 n each, 16 steps of 32). Block 1024 = 16 waves;
// wave w = batch w (all 16 batches co-resident -> denominator is block-local).
// Per step: GEMM1 (own-b, dense global frag loads) -> exp -> E in LDS -> barrier ->
// D-phase (256 thr: 1/sum_b E) -> barrier -> P = E*Dinv -> GEMM2 (dense V frags).
// Epilogue: atomics into pre-zeroed out (4 ns-blocks per address).
__global__ __launch_bounds__(1024, 8) void attn_fused_kernel(
    const unsigned short* __restrict__ qb, const unsigned short* __restrict__ kT,
    const unsigned short* __restrict__ vS, float* __restrict__ out)
{
    __shared__ unsigned short E[BATCH * 16 * EPITCH]; // 20.5 KB: [b][m(16)][n pitch 40]
    __shared__ float Dinv[16 * DPITCH];               // 2.25 KB: [m][n pitch 36]

    const int tid = threadIdx.x, w = tid >> 6, lane = tid & 63;
    const int c = lane & 15, q = lane >> 4;
    const int mt = blockIdx.x & 127, ns = blockIdx.x >> 7;
    const int m0 = mt * 16;
    const int nbase = ns * 512;

    const unsigned short* qb_b = qb + (size_t)w * BSTRIDE;
    const unsigned short* kT_b = kT + (size_t)w * BSTRIDE;
    const unsigned short* vS_b = vS + (size_t)w * BSTRIDE;

    // Persistent Q fragments (pre-scaled by 1/8); lane (c,q): row m0+c, i-chunks swizzled.
    short8 Qf0 = *(const short8*)(qb_b + (m0 + c) * 64 + (q ^ (c & 7)) * 8);
    short8 Qf1 = *(const short8*)(qb_b + (m0 + c) * 64 + ((4 + q) ^ (c & 7)) * 8);

    float4v acc[4];
#pragma unroll
    for (int jt = 0; jt < 4; jt++) acc[jt] = (float4v){0.f, 0.f, 0.f, 0.f};

#pragma unroll 1
    for (int st = 0; st < 16; st++) {
        const int n0 = nbase + st * 32;

        // ---- GEMM1: S^T tile (32n x 16m), K frags straight from global (dense 2KB/wave) ----
        float4v Cf[2];
#pragma unroll
        for (int nt = 0; nt < 2; nt++) {
            const unsigned short* kr = kT_b + (size_t)(n0 + nt * 16 + c) * 64;
            short8 A0 = *(const short8*)(kr + (q ^ (c & 7)) * 8);
            short8 A1 = *(const short8*)(kr + ((4 + q) ^ (c & 7)) * 8);
            float4v d = (float4v){0.f, 0.f, 0.f, 0.f};
            d = __builtin_amdgcn_mfma_f32_16x16x32_bf16(A0, Qf0, d, 0, 0, 0);
            d = __builtin_amdgcn_mfma_f32_16x16x32_bf16(A1, Qf1, d, 0, 0, 0);
            Cf[nt] = d;
        }

        // ---- exp(S) -> bf16 -> E[w][m=c][n]  (C-frag: col=c=m, row=q*4+r=n) ----
#pragma unroll
        for (int nt = 0; nt < 2; nt++) {
            ushort4 e;
            e.x = f2bf(__expf(Cf[nt][0]));
            e.y = f2bf(__expf(Cf[nt][1]));
            e.z = f2bf(__expf(Cf[nt][2]));
            e.w = f2bf(__expf(Cf[nt][3]));
            *(ushort4*)&E[(w * 16 + c) * EPITCH + nt * 16 + q * 4] = e;
        }
        asm volatile("s_waitcnt lgkmcnt(0)" ::: "memory");
        asm volatile("s_barrier" ::: "memory"); // E visible to all waves

        // ---- D-phase: 256 threads = 16 m x 16 n-pairs; sum across 16 batches ----
        if (tid < 256) {
            int m = tid >> 4, np = tid & 15;
            float slo = 0.f, shi = 0.f;
#pragma unroll
            for (int b2 = 0; b2 < BATCH; b2++) {
                unsigned int u = *(const unsigned int*)&E[(b2 * 16 + m) * EPITCH + np * 2];
                shi += __uint_as_float(u & 0xffff0000u); // odd n
                slo += __uint_as_float(u << 16);         // even n
            }
            Dinv[m * DPITCH + np * 2] = __builtin_amdgcn_rcpf(slo);
            Dinv[m * DPITCH + np * 2 + 1] = __builtin_amdgcn_rcpf(shi);
        }
        asm volatile("s_waitcnt lgkmcnt(0)" ::: "memory");
        asm volatile("s_barrier" ::: "memory"); // Dinv visible

        // ---- P = E * Dinv (own-wave rows; one b128 + two b128 reads) ----
        short8 ev = *(const short8*)&E[(w * 16 + c) * EPITCH + q * 8];
        float4v di0 = *(const float4v*)&Dinv[c * DPITCH + q * 8];
        float4v di1 = *(const float4v*)&Dinv[c * DPITCH + q * 8 + 4];
        short8 Pf;
#pragma unroll
        for (int t = 0; t < 4; t++) {
            Pf[t] = (short)f2bf(bf2f((unsigned short)ev[t]) * di0[t]);
            Pf[4 + t] = (short)f2bf(bf2f((unsigned short)ev[4 + t]) * di1[t]);
        }

        // ---- GEMM2: acc += P @ V, V frags dense from tiled vS (1KB/wave each) ----
        const unsigned short* vb = vS_b + (size_t)(ns * 16 + st) * 2048;
#pragma unroll
        for (int jt = 0; jt < 4; jt++) {
            short8 Vf = *(const short8*)(vb + (jt * 16 + c) * 32 + (q ^ (c & 3)) * 8);
            acc[jt] = __builtin_amdgcn_mfma_f32_16x16x32_bf16(Pf, Vf, acc[jt], 0, 0, 0);
        }
    }

    // ---- Epilogue: C/D col=c=j, row=q*4+r=m; 4 ns-blocks accumulate via atomics ----
#pragma unroll
    for (int jt = 0; jt < 4; jt++)
#pragma unroll
        for (int r = 0; r < 4; r++) {
            int m = m0 + q * 4 + r;
            atomicAdd(&out[((size_t)w * CDIM + m) * LDIM + jt * 16 + c], acc[jt][r]);
        }
}

extern "C" void kernel_launch(void* const* d_in, const int* in_sizes, int n_in,
                              void* d_out, int out_size, void* d_ws, size_t ws_size,
                              hipStream_t stream) {
    const float* q = (const float*)d_in[0];
    const float* k = (const float*)d_in[1];
    const float* v = (const float*)d_in[2];
    float* out = (float*)d_out;

    unsigned short* qb = (unsigned short*)d_ws;        // 4 MB bf16 swizzled (q*0.125)
    unsigned short* kT = qb + (size_t)BATCH * BSTRIDE; // 4 MB bf16 swizzled [b][n][i]
    unsigned short* vS = kT + (size_t)BATCH * BSTRIDE; // 4 MB bf16 tiled [b][nb][j][nn]

    prepass_kernel<<<3072, 256, 0, stream>>>(q, k, v, out, qb, kT, vS);
    attn_fused_kernel<<<512, 1024, 0, stream>>>(qb, kT, vS, out);
}

// Round 8
// 124.878 us; speedup vs baseline: 1.2109x; 1.2109x over previous
//
#include <hip/hip_runtime.h>

typedef __attribute__((ext_vector_type(8))) short short8;
typedef __attribute__((ext_vector_type(4))) float float4v;

#define BATCH 16
#define CDIM 2048
#define LDIM 64
#define BSTRIDE (CDIM * LDIM) /* 131072 elems per batch */

#if __has_builtin(__builtin_amdgcn_exp2f)
#define EXPW(x) __builtin_amdgcn_exp2f(x)
#define QSCALE 0.18033688011112042f /* 0.125 * log2(e): exp(S) == exp2(S') */
#else
#define EXPW(x) __expf(x)
#define QSCALE 0.125f
#endif

__device__ __forceinline__ float bf2f(unsigned short u) {
    return __uint_as_float(((unsigned int)u) << 16);
}
__device__ __forceinline__ unsigned short f2bf(float f) {
    unsigned int x = __float_as_uint(f);
    x += 0x7fffu + ((x >> 16) & 1u); // RNE
    return (unsigned short)(x >> 16);
}
// Async global->LDS DMA: 16B/lane, lane i lands at lptr + i*16. lptr wave-uniform.
__device__ __forceinline__ void dma16(const void* g, void* l) {
    __builtin_amdgcn_global_load_lds(
        (const __attribute__((address_space(1))) void*)g,
        (__attribute__((address_space(3))) void*)l, 16, 0, 0);
}

// ---- Prepass (2048 blocks x 256):
//  [0,1024)    q*QSCALE -> swizzled bf16 (chunk j at j^(m&7) within 128B row)
//  [1024,1536) k (64i x 2048n) -> kT[b][n][i] bf16, chunk-swizzled
//  [1536,2048) v (2048n x 64j) -> vS[b][nb][j][nn] bf16, chunk-swizzled
__global__ __launch_bounds__(256) void prepass_kernel(
    const float* __restrict__ q, const float* __restrict__ k, const float* __restrict__ v,
    unsigned short* __restrict__ qb,
    unsigned short* __restrict__ kT, unsigned short* __restrict__ vS)
{
    __shared__ unsigned short T[64][68];
    const int bx = blockIdx.x;
    const int t = threadIdx.x;

    if (bx < 1024) {
        int i = bx * 256 + t; // one 16B out-chunk (8 bf16) per thread
        const float4v* src = (const float4v*)q + (size_t)i * 2;
        float4v x0 = src[0], x1 = src[1];
        unsigned int u0 = f2bf(x0[0] * QSCALE) | ((unsigned)f2bf(x0[1] * QSCALE) << 16);
        unsigned int u1 = f2bf(x0[2] * QSCALE) | ((unsigned)f2bf(x0[3] * QSCALE) << 16);
        unsigned int u2 = f2bf(x1[0] * QSCALE) | ((unsigned)f2bf(x1[1] * QSCALE) << 16);
        unsigned int u3 = f2bf(x1[2] * QSCALE) | ((unsigned)f2bf(x1[3] * QSCALE) << 16);
        int b = i >> 14, r = i & 16383, m = r >> 3, j = r & 7;
        *(uint4*)(qb + (size_t)b * BSTRIDE + m * 64 + (j ^ (m & 7)) * 8) =
            make_uint4(u0, u1, u2, u3);
    } else if (bx < 1536) { // k-transpose: tile = all 64 i x 64 n
        int idx = bx - 1024, b = idx >> 5, n0 = (idx & 31) * 64;
        const float* src = k + (size_t)b * BSTRIDE + (size_t)(t >> 2) * 2048 + n0 + (t & 3) * 16;
#pragma unroll
        for (int kk = 0; kk < 4; kk++) {
            float4v x = *(const float4v*)(src + kk * 4);
#pragma unroll
            for (int e = 0; e < 4; e++)
                T[t >> 2][(t & 3) * 16 + kk * 4 + e] = f2bf(x[e]);
        }
        __syncthreads();
        unsigned short* dst = kT + (size_t)b * BSTRIDE;
        int n = t & 63;
#pragma unroll
        for (int jj = 0; jj < 2; jj++) {
            int j = (t >> 6) * 2 + jj;
            ushort4 g0, g1;
#pragma unroll
            for (int e = 0; e < 4; e++) { g0[e] = T[j * 8 + e][n]; g1[e] = T[j * 8 + 4 + e][n]; }
            *(uint4*)(dst + (size_t)(n0 + n) * 64 + (j ^ (n & 7)) * 8) =
                make_uint4(g0.x | ((unsigned)g0.y << 16), g0.z | ((unsigned)g0.w << 16),
                           g1.x | ((unsigned)g1.y << 16), g1.z | ((unsigned)g1.w << 16));
        }
    } else { // v-transpose: tile = 64 n x 64 j
        int idx = bx - 1536, b = idx >> 5, n0 = (idx & 31) * 64;
        const float* src = v + (size_t)b * BSTRIDE + (size_t)n0 * 64 +
                           (size_t)(t >> 2) * 64 + (t & 3) * 16;
#pragma unroll
        for (int kk = 0; kk < 4; kk++) {
            float4v x = *(const float4v*)(src + kk * 4);
#pragma unroll
            for (int e = 0; e < 4; e++)
                T[t >> 2][(t & 3) * 16 + kk * 4 + e] = f2bf(x[e]); // T[n][j]
        }
        __syncthreads();
        unsigned short* dst = vS + (size_t)b * BSTRIDE;
        int j = t & 63, qc = t >> 6;
#pragma unroll
        for (int nb = 0; nb < 2; nb++) {
            ushort4 g0, g1;
#pragma unroll
            for (int e = 0; e < 4; e++) {
                g0[e] = T[nb * 32 + qc * 8 + e][j];
                g1[e] = T[nb * 32 + qc * 8 + 4 + e][j];
            }
            *(uint4*)(dst + (size_t)(n0 / 32 + nb) * 2048 + j * 32 + (qc ^ (j & 3)) * 8) =
                make_uint4(g0.x | ((unsigned)g0.y << 16), g0.z | ((unsigned)g0.w << 16),
                           g1.x | ((unsigned)g1.y << 16), g1.z | ((unsigned)g1.w << 16));
        }
    }
}

// ---- dinv: Dt[tm][tn] 16x16 frag-direct tiles (512B: c*32 + q*8 -> uint2 of 4 bf16 1/D).
// Grid 1024 = 32 mt(64m) x 32 ng(64n); block 256 = 4 waves; 4 blocks/CU.
// Single-barrier double-buffered pipeline over the 16 batches.
__global__ __launch_bounds__(256, 4) void dinv_kernel(
    const unsigned short* __restrict__ qb, const unsigned short* __restrict__ kT,
    unsigned short* __restrict__ Dt)
{
    __shared__ __align__(16) unsigned char smem[32768]; // Sq[2]@0 (8KB ea), Sk[2]@16384

    const int tid = threadIdx.x, w = tid >> 6, lane = tid & 63;
    const int c = lane & 15, q = lane >> 4;
    const int mt = blockIdx.x & 31, ng = blockIdx.x >> 5;
    const int m0 = mt * 64, n0 = ng * 64;

    float4v Dacc[4];
#pragma unroll
    for (int nt = 0; nt < 4; nt++) Dacc[nt] = (float4v){0.f, 0.f, 0.f, 0.f};

    { // stage batch 0 into buf 0
        const char* qg = (const char*)(qb + (size_t)m0 * 64);
        const char* kg = (const char*)(kT + (size_t)n0 * 64);
        dma16(qg + (w * 2 + 0) * 1024 + lane * 16, (char*)smem + (w * 2 + 0) * 1024);
        dma16(qg + (w * 2 + 1) * 1024 + lane * 16, (char*)smem + (w * 2 + 1) * 1024);
        dma16(kg + (w * 2 + 0) * 1024 + lane * 16, (char*)smem + 16384 + (w * 2 + 0) * 1024);
        dma16(kg + (w * 2 + 1) * 1024 + lane * 16, (char*)smem + 16384 + (w * 2 + 1) * 1024);
    }

    for (int bb = 0; bb < BATCH; bb++) {
        const int p = bb & 1;
        asm volatile("s_waitcnt vmcnt(0)" ::: "memory");
        asm volatile("s_barrier" ::: "memory"); // buf p landed everywhere; buf p^1 free
        if (bb < BATCH - 1) {
            const char* qg = (const char*)(qb + (size_t)(bb + 1) * BSTRIDE + (size_t)m0 * 64);
            const char* kg = (const char*)(kT + (size_t)(bb + 1) * BSTRIDE + (size_t)n0 * 64);
            dma16(qg + (w * 2 + 0) * 1024 + lane * 16, (char*)smem + (p ^ 1) * 8192 + (w * 2 + 0) * 1024);
            dma16(qg + (w * 2 + 1) * 1024 + lane * 16, (char*)smem + (p ^ 1) * 8192 + (w * 2 + 1) * 1024);
            dma16(kg + (w * 2 + 0) * 1024 + lane * 16, (char*)smem + 16384 + (p ^ 1) * 8192 + (w * 2 + 0) * 1024);
            dma16(kg + (w * 2 + 1) * 1024 + lane * 16, (char*)smem + 16384 + (p ^ 1) * 8192 + (w * 2 + 1) * 1024);
        }
        const char* sq = (const char*)smem + p * 8192;
        const char* sk = (const char*)smem + 16384 + p * 8192;
        short8 Qf0 = *(const short8*)(sq + (w * 16 + c) * 128 + ((q) ^ (c & 7)) * 16);
        short8 Qf1 = *(const short8*)(sq + (w * 16 + c) * 128 + ((4 + q) ^ (c & 7)) * 16);
#pragma unroll
        for (int nt = 0; nt < 4; nt++) {
            short8 A0 = *(const short8*)(sk + (nt * 16 + c) * 128 + ((q) ^ (c & 7)) * 16);
            short8 A1 = *(const short8*)(sk + (nt * 16 + c) * 128 + ((4 + q) ^ (c & 7)) * 16);
            float4v d = (float4v){0.f, 0.f, 0.f, 0.f};
            d = __builtin_amdgcn_mfma_f32_16x16x32_bf16(A0, Qf0, d, 0, 0, 0);
            d = __builtin_amdgcn_mfma_f32_16x16x32_bf16(A1, Qf1, d, 0, 0, 0);
#pragma unroll
            for (int r = 0; r < 4; r++) Dacc[nt][r] += EXPW(d[r]);
        }
    }

#pragma unroll
    for (int nt = 0; nt < 4; nt++) {
        unsigned int x = f2bf(__builtin_amdgcn_rcpf(Dacc[nt][0])) |
                         ((unsigned)f2bf(__builtin_amdgcn_rcpf(Dacc[nt][1])) << 16);
        unsigned int y = f2bf(__builtin_amdgcn_rcpf(Dacc[nt][2])) |
                         ((unsigned)f2bf(__builtin_amdgcn_rcpf(Dacc[nt][3])) << 16);
        *(uint2*)((char*)Dt + ((size_t)(mt * 4 + w) * 128 + ng * 4 + nt) * 512 +
                  c * 32 + q * 8) = make_uint2(x, y);
    }
}

// ---- Main: out_b = (exp(S_b)*Dinv) @ V_b. Grid 512 = 16b x 32mt(64m); 2 blocks/CU.
// Block 1024 = 16 waves: g = w>>2 (16m sub), ns = w&3 (512n split, 16 steps of 32).
// One s_barrier/step (DMA issued after barrier), Dt reg-prefetched a step ahead,
// P C->A transform via __shfl (no LDS round-trip). Epilogue: 4-copy LDS reduction.
__global__ __launch_bounds__(1024, 8) void attn_main_kernel(
    const unsigned short* __restrict__ qb, const unsigned short* __restrict__ kT,
    const unsigned short* __restrict__ vS, const unsigned short* __restrict__ Dt,
    float* __restrict__ out)
{
    __shared__ __align__(16) unsigned char smem[65536];
    // staging: Sk[ns][p] @ (ns*2+p)*4096 ; Sv[ns][p] @ 32768+(ns*2+p)*4096
    // epilogue: float[4][4096] over the whole region

    const int tid = threadIdx.x, w = tid >> 6, lane = tid & 63;
    const int c = lane & 15, q = lane >> 4;
    const int g = w >> 2, ns = w & 3;
    const int b = blockIdx.x & 15, mt = blockIdx.x >> 4; // mt 0..31
    const int m0 = mt * 64;
    const int nbase = ns * 512;

    const unsigned short* qb_b = qb + (size_t)b * BSTRIDE;
    const char* kbase = (const char*)(kT + (size_t)b * BSTRIDE);
    const char* vbase = (const char*)(vS + (size_t)b * BSTRIDE);
    char* skb = (char*)smem + (ns * 2) * 4096;
    char* svb = (char*)smem + 32768 + (ns * 2) * 4096;

    short8 Qf0 = *(const short8*)(qb_b + (m0 + g * 16 + c) * 64 + ((q) ^ (c & 7)) * 8);
    short8 Qf1 = *(const short8*)(qb_b + (m0 + g * 16 + c) * 64 + ((4 + q) ^ (c & 7)) * 8);

    float4v acc[4];
#pragma unroll
    for (int jt = 0; jt < 4; jt++) acc[jt] = (float4v){0.f, 0.f, 0.f, 0.f};

    // Dt frag-direct base for this wave: tile (mt*4+g, ns*32 + st*2 + nt)
    const char* dtw = (const char*)Dt + ((size_t)(mt * 4 + g) * 128 + ns * 32) * 512 +
                      c * 32 + q * 8;

    // stage step 0
    dma16(kbase + (size_t)nbase * 128 + g * 1024 + lane * 16, skb + g * 1024);
    dma16(vbase + (size_t)(ns * 16) * 4096 + g * 1024 + lane * 16, svb + g * 1024);
    uint2 du0 = *(const uint2*)(dtw + 0);
    uint2 du1 = *(const uint2*)(dtw + 512);

    for (int st = 0; st < 16; st++) {
        const int p = st & 1;
        asm volatile("s_waitcnt vmcnt(0)" ::: "memory");
        asm volatile("s_barrier" ::: "memory"); // buf p landed; buf p^1 reads done

        uint2 nu0 = du0, nu1 = du1;
        if (st < 15) { // prefetch next step (safe after barrier)
            const int n1 = nbase + (st + 1) * 32;
            dma16(kbase + (size_t)n1 * 128 + g * 1024 + lane * 16,
                  skb + (p ^ 1) * 4096 + g * 1024);
            dma16(vbase + (size_t)(ns * 16 + st + 1) * 4096 + g * 1024 + lane * 16,
                  svb + (p ^ 1) * 4096 + g * 1024);
            nu0 = *(const uint2*)(dtw + (size_t)((st + 1) * 2) * 512);
            nu1 = *(const uint2*)(dtw + (size_t)((st + 1) * 2 + 1) * 512);
        }

        // GEMM1 (S^T) + exp2*Dinv -> packed bf16 pairs pr[nt][rp]
        const char* skp = skb + p * 4096;
        unsigned int pr[2][2];
#pragma unroll
        for (int nt = 0; nt < 2; nt++) {
            short8 A0 = *(const short8*)(skp + (nt * 16 + c) * 128 + ((q) ^ (c & 7)) * 16);
            short8 A1 = *(const short8*)(skp + (nt * 16 + c) * 128 + ((4 + q) ^ (c & 7)) * 16);
            float4v d = (float4v){0.f, 0.f, 0.f, 0.f};
            d = __builtin_amdgcn_mfma_f32_16x16x32_bf16(A0, Qf0, d, 0, 0, 0);
            d = __builtin_amdgcn_mfma_f32_16x16x32_bf16(A1, Qf1, d, 0, 0, 0);
            uint2 u = nt ? du1 : du0;
            float p0 = EXPW(d[0]) * __uint_as_float(u.x << 16);
            float p1 = EXPW(d[1]) * __uint_as_float(u.x & 0xffff0000u);
            float p2 = EXPW(d[2]) * __uint_as_float(u.y << 16);
            float p3 = EXPW(d[3]) * __uint_as_float(u.y & 0xffff0000u);
            pr[nt][0] = f2bf(p0) | ((unsigned)f2bf(p1) << 16);
            pr[nt][1] = f2bf(p2) | ((unsigned)f2bf(p3) << 16);
        }

        // C-frag -> A-frag transform via shfl within the 4 q-lanes of each c.
        // Pf reg t (pair n = q*8+2t): src lane (2*(q&1)+(t>>1))*16+c, pair t&1, nt=q>>1.
        union { unsigned int i[4]; short8 s; } pu;
#pragma unroll
        for (int t = 0; t < 4; t++) {
            int src = (2 * (q & 1) + (t >> 1)) * 16 + c;
            int va = __shfl((int)pr[0][t & 1], src);
            int vb = __shfl((int)pr[1][t & 1], src);
            pu.i[t] = (unsigned int)((q >= 2) ? vb : va);
        }

        // GEMM2: acc += P @ V
        const char* svp = svb + p * 4096;
#pragma unroll
        for (int jt = 0; jt < 4; jt++) {
            short8 Vf = *(const short8*)(svp + (jt * 16 + c) * 64 + ((q) ^ (c & 3)) * 16);
            acc[jt] = __builtin_amdgcn_mfma_f32_16x16x32_bf16(pu.s, Vf, acc[jt], 0, 0, 0);
        }
        du0 = nu0; du1 = nu1;
    }

    // ---- Epilogue: 4 ns-copies in LDS, one sync, sum + coalesced float4 store ----
    __syncthreads(); // all staging reads done; safe to overwrite smem
    {
        float* reg = (float*)smem + ns * 4096; // [m 64][j 64] fp32 per ns
#pragma unroll
        for (int jt = 0; jt < 4; jt++)
#pragma unroll
            for (int r = 0; r < 4; r++)
                reg[(g * 16 + q * 4 + r) * 64 + jt * 16 + c] = acc[jt][r];
    }
    __syncthreads();
    {
        int ml = tid >> 4, j0 = (tid & 15) * 4;
        float4v s = (float4v){0.f, 0.f, 0.f, 0.f};
#pragma unroll
        for (int n2 = 0; n2 < 4; n2++)
            s += *(const float4v*)((float*)smem + n2 * 4096 + ml * 64 + j0);
        *(float4v*)(out + ((size_t)b * CDIM + m0 + ml) * LDIM + j0) = s;
    }
}

extern "C" void kernel_launch(void* const* d_in, const int* in_sizes, int n_in,
                              void* d_out, int out_size, void* d_ws, size_t ws_size,
                              hipStream_t stream) {
    const float* q = (const float*)d_in[0];
    const float* k = (const float*)d_in[1];
    const float* v = (const float*)d_in[2];
    float* out = (float*)d_out;

    unsigned short* qb = (unsigned short*)d_ws;        // 4 MB bf16 swizzled (q*QSCALE)
    unsigned short* kT = qb + (size_t)BATCH * BSTRIDE; // 4 MB bf16 swizzled [b][n][i]
    unsigned short* vS = kT + (size_t)BATCH * BSTRIDE; // 4 MB bf16 tiled [b][nb][j][nn]
    unsigned short* Dt = vS + (size_t)BATCH * BSTRIDE; // 8 MB bf16 1/D frag-direct tiles

    prepass_kernel<<<2048, 256, 0, stream>>>(q, k, v, qb, kT, vS);
    dinv_kernel<<<1024, 256, 0, stream>>>(qb, kT, Dt);
    attn_main_kernel<<<512, 1024, 0, stream>>>(qb, kT, vS, Dt, out);
}